// Round 8
// baseline (528.710 us; speedup 1.0000x reference)
//
#include <hip/hip_runtime.h>

#define S_LEN 2048
#define NHEAD 32
#define HD 80
#define DPAD 96
#define HIDDEN 2560
#define QKV_N 7680

typedef __attribute__((ext_vector_type(8))) short bf16x8;
typedef __attribute__((ext_vector_type(8))) unsigned short u16x8;
typedef __attribute__((ext_vector_type(4))) float f32x4;

__device__ __forceinline__ unsigned short f2bf(float f) {
  unsigned int u = __float_as_uint(f);
  u += 0x7fffu + ((u >> 16) & 1u);   // RNE
  return (unsigned short)(u >> 16);
}
__device__ __forceinline__ float bf2f(unsigned short h) {
  return __uint_as_float(((unsigned int)h) << 16);
}

__device__ __forceinline__ void gload16(const void* g, void* l) {
  __builtin_amdgcn_global_load_lds((const __attribute__((address_space(1))) void*)g,
                                   (__attribute__((address_space(3))) void*)l, 16, 0, 0);
}

// ---------------- fp32 -> bf16 elementwise ----------------
__global__ __launch_bounds__(256) void k_cvt(const float* __restrict__ in,
                                             unsigned short* __restrict__ out, int n4) {
  int i = blockIdx.x * 256 + threadIdx.x;
  if (i >= n4) return;
  float4 v = reinterpret_cast<const float4*>(in)[i];
  ushort4 o;
  o.x = f2bf(v.x); o.y = f2bf(v.y); o.z = f2bf(v.z); o.w = f2bf(v.w);
  reinterpret_cast<ushort4*>(out)[i] = o;
}

// ---------------- fp32 (R x C) -> bf16 transposed (C x R) ----------------
__global__ __launch_bounds__(256) void k_transpose_bf16(const float* __restrict__ in,
                                                        unsigned short* __restrict__ out,
                                                        int R, int C) {
  __shared__ float tile[64][65];
  int tc = blockIdx.x * 64, tr = blockIdx.y * 64;
  for (int i = threadIdx.x; i < 64 * 64; i += 256) {
    int r = i >> 6, c = i & 63;
    tile[r][c] = in[(size_t)(tr + r) * C + (tc + c)];
  }
  __syncthreads();
  for (int i = threadIdx.x; i < 64 * 64; i += 256) {
    int r = i >> 6, c = i & 63;
    out[(size_t)(tc + r) * R + (tr + c)] = f2bf(tile[c][r]);
  }
}

// ---------------- reg-pipelined bf16 GEMM: C = A(MxK)*Bt(NxK)^T + bias ------
// BM x BM tile, BK=32, BM/32 waves, 4-deep circular LDS (R4-verified swizzle,
// 0 bank conflicts).  Register-level fragment double-buffer: during tile t,
// prefetch tile t+1's fragments into the alternate reg set (ds_reads overlap
// the MFMA cluster), stage tile t+3 via global_load_lds, run t's 16*MF/4 MFMAs.
// One barrier + one counted vmcnt per tile.
// vmcnt inventory (4 loads per staged tile): entry of t has only (t+2) in
// flight; during t stage (t+3) -> 8 in flight; end-of-t vmcnt(4) drains
// (t+2) -- needed because frags(t+2) are read during t+1.  vmcnt(0) for the
// t+3>=NT tail.  Stage target buf (t+3)&3 = buf (t-1)&3, whose last ds_reads
// (frag prefetch of t-1, issued during t-2) are >= 2 barriers old.
template <int BM>
__global__ __launch_bounds__(BM / 32 * 64, 2)
void k_gemm_p(const unsigned short* __restrict__ A,
              const unsigned short* __restrict__ Bt,
              const float* __restrict__ bias,
              unsigned short* __restrict__ Cbf,
              float* __restrict__ Cf,
              int M, int N, int K, int out_f32) {
  constexpr int NW = BM / 32;        // waves (4 for BM=128)
  constexpr int NCW = NW / 2;        // waves along N
  constexpr int MF = BM / 32;        // per-wave M fragments
  constexpr int TE = BM * 32;        // elems per tile buffer
  __shared__ unsigned short sA[4][TE];
  __shared__ unsigned short sB[4][TE];
  const int nbn = N / BM;
  const int nwg = (M / BM) * nbn;
  int wg = blockIdx.x;
  const int cpx = nwg >> 3;          // nwg % 8 == 0 for all calls
  wg = (wg & 7) * cpx + (wg >> 3);
  const int bm = wg / nbn, bn = wg - bm * nbn;
  const int tid = threadIdx.x;
  const int lane = tid & 63, wave = tid >> 6;
  const int wr = wave / NCW, wc = wave % NCW;
  const int lc = lane & 15, lr = lane >> 4;

  // R4-verified staging source (inverse-swizzled)
  const int sub = (lane & 7) ^ (lane >> 3);
  const int rstage = wave * 16 + ((lane >> 3) << 1) + (sub >> 2);
  const int cstage = (sub & 3) * 8;
  const unsigned short* Agp = A + (size_t)(bm * BM + rstage) * K + cstage;
  const unsigned short* Bgp = Bt + (size_t)(bn * BM + rstage) * K + cstage;
  const size_t halfoff = (size_t)(BM / 2) * K;

  // R4-verified fragment-read lane offset (bytes)
  const int loff = ((lc >> 1) << 7) + (((((lc & 1) << 2) | lr) ^ (lc >> 1)) << 4);

  f32x4 acc[MF][4];
  const f32x4 zero = {0.f, 0.f, 0.f, 0.f};
#pragma unroll
  for (int m = 0; m < MF; ++m)
#pragma unroll
    for (int n = 0; n < 4; ++n) acc[m][n] = zero;

  auto stage = [&](int buf, int t) {
    gload16(Agp + t * 32, &sA[buf][wave * 512]);
    gload16(Agp + halfoff + t * 32, &sA[buf][BM * 16 + wave * 512]);
    gload16(Bgp + t * 32, &sB[buf][wave * 512]);
    gload16(Bgp + halfoff + t * 32, &sB[buf][BM * 16 + wave * 512]);
  };
  auto rdfrags = [&](int buf, bf16x8 (&af)[MF], bf16x8 (&bf)[4]) {
    const char* bufA = (const char*)&sA[buf][0];
    const char* bufB = (const char*)&sB[buf][0];
#pragma unroll
    for (int ni = 0; ni < 4; ++ni)
      bf[ni] = *(const bf16x8*)(bufB + ((wc * 64 + ni * 16) << 6) + loff);
#pragma unroll
    for (int mi = 0; mi < MF; ++mi)
      af[mi] = *(const bf16x8*)(bufA + ((wr * (BM / 2) + mi * 16) << 6) + loff);
  };

  const int NT = K >> 5;   // 80 for K=2560 (even)

  // prologue: stage tiles 0,1,2; wait for 0,1 (tile 2 stays in flight)
  stage(0, 0);
  stage(1, 1);
  stage(2, 2);
  asm volatile("s_waitcnt vmcnt(4)" ::: "memory");
  __builtin_amdgcn_s_barrier();
  __builtin_amdgcn_sched_barrier(0);

  bf16x8 afX[MF], bfX[4], afY[MF], bfY[4];
  rdfrags(0, afX, bfX);

  for (int tt = 0; tt < NT; tt += 2) {
    // ---- even tile t = tt: consume X, prefetch t+1 into Y ----
    {
      const int t = tt;
      if (t + 1 < NT) rdfrags((t + 1) & 3, afY, bfY);
      if (t + 3 < NT) stage((t + 3) & 3, t + 3);
      __builtin_amdgcn_s_setprio(1);
#pragma unroll
      for (int mi = 0; mi < MF; ++mi)
#pragma unroll
        for (int ni = 0; ni < 4; ++ni)
          acc[mi][ni] = __builtin_amdgcn_mfma_f32_16x16x32_bf16(afX[mi], bfX[ni], acc[mi][ni], 0, 0, 0);
      __builtin_amdgcn_s_setprio(0);
      if (t + 3 < NT) asm volatile("s_waitcnt vmcnt(4)" ::: "memory");
      else            asm volatile("s_waitcnt vmcnt(0)" ::: "memory");
      __builtin_amdgcn_s_barrier();
      __builtin_amdgcn_sched_barrier(0);
    }
    // ---- odd tile t = tt+1: consume Y, prefetch t+1 into X ----
    {
      const int t = tt + 1;
      if (t + 1 < NT) rdfrags((t + 1) & 3, afX, bfX);
      if (t + 3 < NT) stage((t + 3) & 3, t + 3);
      __builtin_amdgcn_s_setprio(1);
#pragma unroll
      for (int mi = 0; mi < MF; ++mi)
#pragma unroll
        for (int ni = 0; ni < 4; ++ni)
          acc[mi][ni] = __builtin_amdgcn_mfma_f32_16x16x32_bf16(afY[mi], bfY[ni], acc[mi][ni], 0, 0, 0);
      __builtin_amdgcn_s_setprio(0);
      if (t + 3 < NT) asm volatile("s_waitcnt vmcnt(4)" ::: "memory");
      else            asm volatile("s_waitcnt vmcnt(0)" ::: "memory");
      __builtin_amdgcn_s_barrier();
      __builtin_amdgcn_sched_barrier(0);
    }
  }

  // epilogue: bias + store
  const int rowb = bm * BM + wr * (BM / 2);
  const int colb = bn * BM + wc * 64;
#pragma unroll
  for (int ni = 0; ni < 4; ++ni) {
    const int col = colb + ni * 16 + lc;
    const float bv = bias[col];
#pragma unroll
    for (int mf = 0; mf < MF; ++mf) {
#pragma unroll
      for (int jj = 0; jj < 4; ++jj) {
        const int row = rowb + mf * 16 + lr * 4 + jj;
        const float v = acc[mf][ni][jj] + bv;
        if (out_f32) Cf[(size_t)row * N + col] = v;
        else Cbf[(size_t)row * N + col] = f2bf(v);
      }
    }
  }
}

// ---------------- RoPE + head split: qkv -> Q (scaled), K, V^T ----------------
__global__ __launch_bounds__(256) void k_rope(const unsigned short* __restrict__ qkv,
                                              unsigned short* __restrict__ Qw,
                                              unsigned short* __restrict__ Kw,
                                              unsigned short* __restrict__ Vt) {
  const int blk = blockIdx.x;
  const int sc = blk & 31;
  const int bh = blk >> 5;
  const int b = bh >> 5, h = bh & 31;
  const int s0 = sc * 64;
  __shared__ float cs0[64][16], sn0[64][16];
  __shared__ unsigned short vbuf[64][82];
  const int tid = threadIdx.x;
  for (int i = tid; i < 64 * 16; i += 256) {
    int sl = i >> 4, fi = i & 15;
    float ang = (float)(s0 + sl) * __expf(-(float)fi * 0.575646273248511421f);
    cs0[sl][fi] = cosf(ang);
    sn0[sl][fi] = sinf(ang);
  }
  __syncthreads();
  const size_t row0 = (size_t)(b * S_LEN + s0) * QKV_N;
  const size_t obase = ((size_t)bh * S_LEN + s0) * DPAD;
  for (int i = tid; i < 64 * DPAD; i += 256) {
    int sl = i / DPAD, d = i - sl * DPAD;
    float qv = 0.f, kv = 0.f;
    if (d < HD) {
      const unsigned short* rp = qkv + row0 + (size_t)sl * QKV_N + h * HD;
      float q = bf2f(rp[d]), k = bf2f(rp[HIDDEN + d]);
      if (d < 16) {
        float c = cs0[sl][d], s = sn0[sl][d];
        float q2 = bf2f(rp[d + 16]), k2 = bf2f(rp[HIDDEN + d + 16]);
        qv = q * c - q2 * s;
        kv = k * c - k2 * s;
      } else if (d < 32) {
        float c = cs0[sl][d - 16], s = sn0[sl][d - 16];
        float q1 = bf2f(rp[d - 16]), k1 = bf2f(rp[HIDDEN + d - 16]);
        qv = q * c + q1 * s;
        kv = k * c + k1 * s;
      } else {
        qv = q; kv = k;
      }
    }
    Qw[obase + (size_t)sl * DPAD + d] = f2bf(qv * 0.111803398874989485f); // * 80^-0.5
    Kw[obase + (size_t)sl * DPAD + d] = f2bf(kv);
  }
  for (int i = tid; i < 64 * HD; i += 256) {
    int sl = i / HD, d = i - sl * HD;
    vbuf[sl][d] = qkv[row0 + (size_t)sl * QKV_N + 2 * HIDDEN + h * HD + d];
  }
  __syncthreads();
  const size_t vtb = (size_t)bh * DPAD * S_LEN + s0;
  for (int i = tid; i < DPAD * 64; i += 256) {
    int d = i >> 6, sl = i & 63;
    Vt[vtb + (size_t)d * S_LEN + sl] = (d < HD) ? vbuf[sl][d] : (unsigned short)0;
  }
}

// ---------------- flash attention (causal), QBLK=128, KVBLK=64 ----------------
__global__ __launch_bounds__(256, 2) void k_attn(const unsigned short* __restrict__ Qw,
                                                 const unsigned short* __restrict__ Kw,
                                                 const unsigned short* __restrict__ Vt,
                                                 unsigned short* __restrict__ O) {
  __shared__ unsigned short sK[2][64 * 104];
  __shared__ unsigned short sV[2][80 * 72];
  __shared__ unsigned short sP[4][16 * 72];
  const int p = blockIdx.x;
  const int bh = blockIdx.y;
  const int b = bh >> 5, h = bh & 31;
  const int tid = threadIdx.x;
  const int wave = tid >> 6, lane = tid & 63;
  const int lr = lane >> 4, lc = lane & 15;
  unsigned short* Pw = &sP[wave][0];

  const unsigned short* Kh = Kw + (size_t)bh * S_LEN * DPAD;
  const unsigned short* Vh = Vt + (size_t)bh * DPAD * S_LEN;
  const unsigned short* Qh = Qw + (size_t)bh * S_LEN * DPAD;

  const int kr = tid >> 2, kc = (tid & 3) * 24;
  const int vr = tid >> 3, vc = (tid & 7) * 8;

  u16x8 kst0, kst1, kst2, vst0, vst1, vst2;
  auto gload = [&](int t) {
    const unsigned short* Kg = Kh + ((size_t)(t * 64 + kr)) * DPAD + kc;
    kst0 = *(const u16x8*)(Kg);
    kst1 = *(const u16x8*)(Kg + 8);
    kst2 = *(const u16x8*)(Kg + 16);
    const unsigned short* Vg = Vh + (size_t)vr * S_LEN + t * 64 + vc;
    vst0 = *(const u16x8*)(Vg);
    vst1 = *(const u16x8*)(Vg + 32 * S_LEN);
    if (tid < 128) vst2 = *(const u16x8*)(Vg + (size_t)64 * S_LEN);
  };
  auto swrite = [&](int buf) {
    *(u16x8*)&sK[buf][kr * 104 + kc] = kst0;
    *(u16x8*)&sK[buf][kr * 104 + kc + 8] = kst1;
    *(u16x8*)&sK[buf][kr * 104 + kc + 16] = kst2;
    *(u16x8*)&sV[buf][vr * 72 + vc] = vst0;
    *(u16x8*)&sV[buf][(vr + 32) * 72 + vc] = vst1;
    if (tid < 128) *(u16x8*)&sV[buf][(vr + 64) * 72 + vc] = vst2;
  };

  const f32x4 zero = {0.f, 0.f, 0.f, 0.f};

#pragma unroll 1
  for (int qi = 0; qi < 2; ++qi) {
    const int qt = qi ? (15 - p) : p;
    const int nt = 2 * qt + 2;
    const int wbase = qt * 128 + wave * 32;

    bf16x8 qf[2][3];
#pragma unroll
    for (int m = 0; m < 2; ++m)
#pragma unroll
      for (int ks = 0; ks < 3; ++ks)
        qf[m][ks] = *(const bf16x8*)&Qh[(size_t)(wbase + m * 16 + lc) * DPAD + ks * 32 + lr * 8];

    f32x4 oacc[2][5];
#pragma unroll
    for (int m = 0; m < 2; ++m)
#pragma unroll
      for (int n = 0; n < 5; ++n) oacc[m][n] = zero;
    float mrun[2] = {-1e30f, -1e30f}, lrun[2] = {0.f, 0.f};

    gload(0);
    __syncthreads();
    swrite(0);
    int cur = 0;

#pragma unroll 1
    for (int t = 0; t < nt; ++t) {
      __syncthreads();
      if (t + 1 < nt) gload(t + 1);
      const int ktb = t * 64;
      const bool act0 = ktb <= wbase + 15;
      const bool act1 = ktb <= wbase + 31;
      if (act1) {
        const unsigned short* Kc = sK[cur];
        const unsigned short* Vc = sV[cur];
        f32x4 sf[2][4];
#pragma unroll
        for (int n = 0; n < 4; ++n) {
          sf[0][n] = zero; sf[1][n] = zero;
#pragma unroll
          for (int ks = 0; ks < 3; ++ks) {
            bf16x8 kf = *(const bf16x8*)&Kc[(n * 16 + lc) * 104 + ks * 32 + lr * 8];
            if (act0) sf[0][n] = __builtin_amdgcn_mfma_f32_16x16x32_bf16(kf, qf[0][ks], sf[0][n], 0, 0, 0);
            sf[1][n] = __builtin_amdgcn_mfma_f32_16x16x32_bf16(kf, qf[1][ks], sf[1][n], 0, 0, 0);
          }
        }
        bf16x8 vf[5][2];
#pragma unroll
        for (int n = 0; n < 5; ++n)
#pragma unroll
          for (int ks = 0; ks < 2; ++ks)
            vf[n][ks] = *(const bf16x8*)&Vc[(n * 16 + lc) * 72 + ks * 32 + lr * 8];
#pragma unroll
        for (int m = 0; m < 2; ++m) {
          if (m == 0 && !act0) continue;
          const int qrow0 = wbase + m * 16;
          if (ktb + 63 > qrow0) {
#pragma unroll
            for (int n = 0; n < 4; ++n)
#pragma unroll
              for (int j = 0; j < 4; ++j)
                if (ktb + n * 16 + lr * 4 + j > qrow0 + lc) sf[m][n][j] = -1e30f;
          }
          float t0 = sf[m][0][0];
#pragma unroll
          for (int n = 0; n < 4; ++n)
#pragma unroll
            for (int j = 0; j < 4; ++j) t0 = fmaxf(t0, sf[m][n][j]);
          t0 = fmaxf(t0, __shfl_xor(t0, 16));
          t0 = fmaxf(t0, __shfl_xor(t0, 32));
          const float nm = fmaxf(mrun[m], t0);
          const float corrq = __expf(mrun[m] - nm);
          mrun[m] = nm;
          float ps = 0.f;
#pragma unroll
          for (int n = 0; n < 4; ++n)
#pragma unroll
            for (int j = 0; j < 4; ++j) {
              float e = __expf(sf[m][n][j] - nm);
              sf[m][n][j] = e;
              ps += e;
            }
          ps += __shfl_xor(ps, 16);
          ps += __shfl_xor(ps, 32);
          lrun[m] = lrun[m] * corrq + ps;
          float cj[4];
#pragma unroll
          for (int j = 0; j < 4; ++j) cj[j] = __shfl(corrq, lr * 4 + j, 16);
#pragma unroll
          for (int n = 0; n < 5; ++n)
#pragma unroll
            for (int j = 0; j < 4; ++j) oacc[m][n][j] *= cj[j];
#pragma unroll
          for (int n = 0; n < 4; ++n) {
            unsigned lo = (unsigned)f2bf(sf[m][n][0]) | ((unsigned)f2bf(sf[m][n][1]) << 16);
            unsigned hi = (unsigned)f2bf(sf[m][n][2]) | ((unsigned)f2bf(sf[m][n][3]) << 16);
            uint2 u; u.x = lo; u.y = hi;
            *(uint2*)&Pw[lc * 72 + n * 16 + lr * 4] = u;
          }
          asm volatile("" ::: "memory");
          bf16x8 pa0 = *(const bf16x8*)&Pw[lc * 72 + lr * 8];
          bf16x8 pa1 = *(const bf16x8*)&Pw[lc * 72 + 32 + lr * 8];
#pragma unroll
          for (int n = 0; n < 5; ++n) {
            oacc[m][n] = __builtin_amdgcn_mfma_f32_16x16x32_bf16(pa0, vf[n][0], oacc[m][n], 0, 0, 0);
            oacc[m][n] = __builtin_amdgcn_mfma_f32_16x16x32_bf16(pa1, vf[n][1], oacc[m][n], 0, 0, 0);
          }
          asm volatile("" ::: "memory");
        }
      }
      if (t + 1 < nt) swrite(cur ^ 1);
      cur ^= 1;
    }

#pragma unroll
    for (int m = 0; m < 2; ++m) {
      float linv[4];
#pragma unroll
      for (int j = 0; j < 4; ++j) {
        float lj = __shfl(lrun[m], lr * 4 + j, 16);
        linv[j] = 1.f / lj;
      }
      const int q0 = wbase + m * 16 + lr * 4;
#pragma unroll
      for (int n = 0; n < 5; ++n) {
        const int d = n * 16 + lc;
#pragma unroll
        for (int j = 0; j < 4; ++j)
          O[((size_t)(b * S_LEN) + q0 + j) * HIDDEN + h * HD + d] = f2bf(oacc[m][n][j] * linv[j]);
      }
    }
  }
}

extern "C" void kernel_launch(void* const* d_in, const int* in_sizes, int n_in,
                              void* d_out, int out_size, void* d_ws, size_t ws_size,
                              hipStream_t stream) {
  (void)in_sizes; (void)n_in; (void)out_size; (void)ws_size;
  const float* hidden  = (const float*)d_in[1];
  const float* w_qkv   = (const float*)d_in[2];
  const float* b_qkv   = (const float*)d_in[3];
  const float* w_dense = (const float*)d_in[4];
  const float* b_dense = (const float*)d_in[5];
  char* ws = (char*)d_ws;
  unsigned short* Abf   = (unsigned short*)(ws + 0);          // 4096x2560 bf16
  unsigned short* Wqkvt = (unsigned short*)(ws + 20971520);   // 7680x2560 bf16
  unsigned short* Wdt   = (unsigned short*)(ws + 60293120);   // 2560x2560 bf16
  unsigned short* QKVb  = (unsigned short*)(ws + 73400320);   // 4096x7680 bf16
  unsigned short* Qw    = (unsigned short*)(ws + 136314880);  // 64x2048x96 bf16
  unsigned short* Kw    = (unsigned short*)(ws + 161480704);
  unsigned short* Vt    = (unsigned short*)(ws + 186646528);
  unsigned short* Obf   = (unsigned short*)(ws + 211812352);  // 4096x2560 bf16

  k_cvt<<<10240, 256, 0, stream>>>(hidden, Abf, 2621440);
  k_transpose_bf16<<<dim3(120, 40), 256, 0, stream>>>(w_qkv, Wqkvt, 2560, 7680);
  k_transpose_bf16<<<dim3(40, 40), 256, 0, stream>>>(w_dense, Wdt, 2560, 2560);
  k_gemm_p<128><<<1920, 256, 0, stream>>>(Abf, Wqkvt, b_qkv, QKVb, nullptr, 4096, 7680, 2560, 0);
  k_rope<<<2048, 256, 0, stream>>>(QKVb, Qw, Kw, Vt);
  k_attn<<<dim3(8, 64), 256, 0, stream>>>(Qw, Kw, Vt, Obf);
  k_gemm_p<128><<<640, 256, 0, stream>>>(Obf, Wdt, b_dense, nullptr, (float*)d_out, 4096, 2560, 2560, 1);
}

// Round 10
// 426.044 us; speedup vs baseline: 1.2410x; 1.2410x over previous
//
#include <hip/hip_runtime.h>

#define S_LEN 2048
#define NHEAD 32
#define HD 80
#define DPAD 96
#define HIDDEN 2560
#define QKV_N 7680

typedef __attribute__((ext_vector_type(8))) short bf16x8;
typedef __attribute__((ext_vector_type(8))) unsigned short u16x8;
typedef __attribute__((ext_vector_type(4))) float f32x4;

__device__ __forceinline__ unsigned short f2bf(float f) {
  unsigned int u = __float_as_uint(f);
  u += 0x7fffu + ((u >> 16) & 1u);   // RNE
  return (unsigned short)(u >> 16);
}
__device__ __forceinline__ float bf2f(unsigned short h) {
  return __uint_as_float(((unsigned int)h) << 16);
}

__device__ __forceinline__ void gload16(const void* g, void* l) {
  __builtin_amdgcn_global_load_lds((const __attribute__((address_space(1))) void*)g,
                                   (__attribute__((address_space(3))) void*)l, 16, 0, 0);
}

// ---------------- fp32 -> bf16 elementwise ----------------
__global__ __launch_bounds__(256) void k_cvt(const float* __restrict__ in,
                                             unsigned short* __restrict__ out, int n4) {
  int i = blockIdx.x * 256 + threadIdx.x;
  if (i >= n4) return;
  float4 v = reinterpret_cast<const float4*>(in)[i];
  ushort4 o;
  o.x = f2bf(v.x); o.y = f2bf(v.y); o.z = f2bf(v.z); o.w = f2bf(v.w);
  reinterpret_cast<ushort4*>(out)[i] = o;
}

// ---------------- fp32 (R x C) -> bf16 transposed (C x R) ----------------
__global__ __launch_bounds__(256) void k_transpose_bf16(const float* __restrict__ in,
                                                        unsigned short* __restrict__ out,
                                                        int R, int C) {
  __shared__ float tile[64][65];
  int tc = blockIdx.x * 64, tr = blockIdx.y * 64;
  for (int i = threadIdx.x; i < 64 * 64; i += 256) {
    int r = i >> 6, c = i & 63;
    tile[r][c] = in[(size_t)(tr + r) * C + (tc + c)];
  }
  __syncthreads();
  for (int i = threadIdx.x; i < 64 * 64; i += 256) {
    int r = i >> 6, c = i & 63;
    out[(size_t)(tc + r) * R + (tr + c)] = f2bf(tile[c][r]);
  }
}

// ---------------- gemm1 (QKV): 256x256, BK=32, R4-exact structure -----------
// 8 waves, 4-deep circular LDS, single entry barrier + counted vmcnt(8),
// R4-verified swizzle (0 bank conflicts), setprio around 32-MFMA cluster.
__global__ __launch_bounds__(512, 2)
void k_gemm_qkv(const unsigned short* __restrict__ A,
                const unsigned short* __restrict__ Bt,
                const float* __restrict__ bias,
                unsigned short* __restrict__ Cbf,
                int M, int N, int K) {
  __shared__ unsigned short sA[4][8192];
  __shared__ unsigned short sB[4][8192];
  const int nbn = N >> 8;
  const int nwg = (M >> 8) * nbn;
  int wg = blockIdx.x;
  const int cpx = nwg >> 3;          // nwg % 8 == 0
  wg = (wg & 7) * cpx + (wg >> 3);
  const int bm = wg / nbn, bn = wg - bm * nbn;
  const int tid = threadIdx.x;
  const int lane = tid & 63, wave = tid >> 6;
  const int wr = wave >> 2, wc = wave & 3;
  const int lc = lane & 15, lr = lane >> 4;

  const int sub = (lane & 7) ^ (lane >> 3);
  const int rstage = wave * 16 + ((lane >> 3) << 1) + (sub >> 2);
  const int cstage = (sub & 3) * 8;
  const unsigned short* Agp = A + (size_t)(bm * 256 + rstage) * K + cstage;
  const unsigned short* Bgp = Bt + (size_t)(bn * 256 + rstage) * K + cstage;
  const size_t halfoff = (size_t)128 * K;

  const int loff = ((lc >> 1) << 7) + (((((lc & 1) << 2) | lr) ^ (lc >> 1)) << 4);

  f32x4 acc[8][4];
  const f32x4 zero = {0.f, 0.f, 0.f, 0.f};
#pragma unroll
  for (int m = 0; m < 8; ++m)
#pragma unroll
    for (int n = 0; n < 4; ++n) acc[m][n] = zero;

  auto stage = [&](int buf, int t) {
    gload16(Agp + t * 32, &sA[buf][wave * 512]);
    gload16(Agp + halfoff + t * 32, &sA[buf][4096 + wave * 512]);
    gload16(Bgp + t * 32, &sB[buf][wave * 512]);
    gload16(Bgp + halfoff + t * 32, &sB[buf][4096 + wave * 512]);
  };

  const int NT = K >> 5;   // 80
#pragma unroll
  for (int t = 0; t < 3; ++t) stage(t, t);

  const int nj = NT >> 2;
  for (int j = 0; j < nj; ++j) {
#pragma unroll
    for (int to = 0; to < 4; ++to) {
      const int t = (j << 2) + to;
      if (t < NT - 2)       asm volatile("s_waitcnt vmcnt(8)" ::: "memory");
      else if (t == NT - 2) asm volatile("s_waitcnt vmcnt(4)" ::: "memory");
      else                  asm volatile("s_waitcnt vmcnt(0)" ::: "memory");
      __builtin_amdgcn_s_barrier();
      asm volatile("" ::: "memory");

      const char* bufA = (const char*)&sA[to][0];
      const char* bufB = (const char*)&sB[to][0];
      bf16x8 af[8], bfr[4];
#pragma unroll
      for (int mi = 0; mi < 8; ++mi)
        af[mi] = *(const bf16x8*)(bufA + ((wr * 128 + mi * 16) << 6) + loff);
#pragma unroll
      for (int ni = 0; ni < 4; ++ni)
        bfr[ni] = *(const bf16x8*)(bufB + ((wc * 64 + ni * 16) << 6) + loff);

      if (t + 3 < NT) stage((to + 3) & 3, t + 3);

      asm volatile("s_waitcnt lgkmcnt(0)" ::: "memory");
      __builtin_amdgcn_sched_barrier(0);
      __builtin_amdgcn_s_setprio(1);
#pragma unroll
      for (int mi = 0; mi < 8; ++mi)
#pragma unroll
        for (int ni = 0; ni < 4; ++ni)
          acc[mi][ni] = __builtin_amdgcn_mfma_f32_16x16x32_bf16(af[mi], bfr[ni], acc[mi][ni], 0, 0, 0);
      __builtin_amdgcn_s_setprio(0);
    }
  }

  const int rowb = bm * 256 + wr * 128;
  const int colb = bn * 256 + wc * 64;
#pragma unroll
  for (int ni = 0; ni < 4; ++ni) {
    const int col = colb + ni * 16 + lc;
    const float bv = bias[col];
#pragma unroll
    for (int mf = 0; mf < 8; ++mf) {
#pragma unroll
      for (int jj = 0; jj < 4; ++jj) {
        const int row = rowb + mf * 16 + lr * 4 + jj;
        Cbf[(size_t)row * N + col] = f2bf(acc[mf][ni][jj] + bv);
      }
    }
  }
}

// ---------------- gemm2 (out-proj): 128x128, 2-deep LDS, full residency -----
// 4 waves, 32 KB LDS, __launch_bounds__(256,4) -> 4 blocks/CU, all 640 blocks
// co-resident (no tail fill).  Drain vmcnt(0) per tile; 16 waves/CU TLP covers
// the drain.  Stage(t+1) issues right after the entry barrier (buf ob's t-1
// frags fully consumed before the barrier).
__global__ __launch_bounds__(256, 4)
void k_gemm_out(const unsigned short* __restrict__ A,
                const unsigned short* __restrict__ Bt,
                const float* __restrict__ bias,
                float* __restrict__ Cf,
                int M, int N, int K) {
  __shared__ unsigned short sA[2][4096];
  __shared__ unsigned short sB[2][4096];
  const int nbn = N >> 7;            // 20
  const int nwg = (M >> 7) * nbn;    // 640, % 8 == 0
  int wg = blockIdx.x;
  const int cpx = nwg >> 3;
  wg = (wg & 7) * cpx + (wg >> 3);
  const int bm = wg / nbn, bn = wg - bm * nbn;
  const int tid = threadIdx.x;
  const int lane = tid & 63, wave = tid >> 6;
  const int wr = wave >> 1, wc = wave & 1;
  const int lc = lane & 15, lr = lane >> 4;

  const int sub = (lane & 7) ^ (lane >> 3);
  const int rstage = wave * 16 + ((lane >> 3) << 1) + (sub >> 2);
  const int cstage = (sub & 3) * 8;
  const unsigned short* Agp = A + (size_t)(bm * 128 + rstage) * K + cstage;
  const unsigned short* Bgp = Bt + (size_t)(bn * 128 + rstage) * K + cstage;
  const size_t halfoff = (size_t)64 * K;

  const int loff = ((lc >> 1) << 7) + (((((lc & 1) << 2) | lr) ^ (lc >> 1)) << 4);

  f32x4 acc[4][4];
  const f32x4 zero = {0.f, 0.f, 0.f, 0.f};
#pragma unroll
  for (int m = 0; m < 4; ++m)
#pragma unroll
    for (int n = 0; n < 4; ++n) acc[m][n] = zero;

  auto stage = [&](int buf, int t) {
    gload16(Agp + t * 32, &sA[buf][wave * 512]);
    gload16(Agp + halfoff + t * 32, &sA[buf][2048 + wave * 512]);
    gload16(Bgp + t * 32, &sB[buf][wave * 512]);
    gload16(Bgp + halfoff + t * 32, &sB[buf][2048 + wave * 512]);
  };

  const int NT = K >> 5;   // 80
  stage(0, 0);
  for (int t = 0; t < NT; ++t) {
    asm volatile("s_waitcnt vmcnt(0)" ::: "memory");
    __builtin_amdgcn_s_barrier();
    asm volatile("" ::: "memory");
    if (t + 1 < NT) stage((t + 1) & 1, t + 1);
    const char* bufA = (const char*)&sA[t & 1][0];
    const char* bufB = (const char*)&sB[t & 1][0];
    bf16x8 af[4], bfr[4];
#pragma unroll
    for (int mi = 0; mi < 4; ++mi)
      af[mi] = *(const bf16x8*)(bufA + ((wr * 64 + mi * 16) << 6) + loff);
#pragma unroll
    for (int ni = 0; ni < 4; ++ni)
      bfr[ni] = *(const bf16x8*)(bufB + ((wc * 64 + ni * 16) << 6) + loff);
    asm volatile("s_waitcnt lgkmcnt(0)" ::: "memory");
    __builtin_amdgcn_sched_barrier(0);
    __builtin_amdgcn_s_setprio(1);
#pragma unroll
    for (int mi = 0; mi < 4; ++mi)
#pragma unroll
      for (int ni = 0; ni < 4; ++ni)
        acc[mi][ni] = __builtin_amdgcn_mfma_f32_16x16x32_bf16(af[mi], bfr[ni], acc[mi][ni], 0, 0, 0);
    __builtin_amdgcn_s_setprio(0);
  }

  const int rowb = bm * 128 + wr * 64;
  const int colb = bn * 128 + wc * 64;
#pragma unroll
  for (int ni = 0; ni < 4; ++ni) {
    const int col = colb + ni * 16 + lc;
    const float bv = bias[col];
#pragma unroll
    for (int mf = 0; mf < 4; ++mf) {
#pragma unroll
      for (int jj = 0; jj < 4; ++jj) {
        const int row = rowb + mf * 16 + lr * 4 + jj;
        Cf[(size_t)row * N + col] = acc[mf][ni][jj] + bv;
      }
    }
  }
}

// ---------------- RoPE + head split: qkv -> Q (scaled), K, V^T ----------------
__global__ __launch_bounds__(256) void k_rope(const unsigned short* __restrict__ qkv,
                                              unsigned short* __restrict__ Qw,
                                              unsigned short* __restrict__ Kw,
                                              unsigned short* __restrict__ Vt) {
  const int blk = blockIdx.x;
  const int sc = blk & 31;
  const int bh = blk >> 5;
  const int b = bh >> 5, h = bh & 31;
  const int s0 = sc * 64;
  __shared__ float cs0[64][16], sn0[64][16];
  __shared__ unsigned short vbuf[64][82];
  const int tid = threadIdx.x;
  for (int i = tid; i < 64 * 16; i += 256) {
    int sl = i >> 4, fi = i & 15;
    float ang = (float)(s0 + sl) * __expf(-(float)fi * 0.575646273248511421f);
    cs0[sl][fi] = cosf(ang);
    sn0[sl][fi] = sinf(ang);
  }
  __syncthreads();
  const size_t row0 = (size_t)(b * S_LEN + s0) * QKV_N;
  const size_t obase = ((size_t)bh * S_LEN + s0) * DPAD;
  for (int i = tid; i < 64 * DPAD; i += 256) {
    int sl = i / DPAD, d = i - sl * DPAD;
    float qv = 0.f, kv = 0.f;
    if (d < HD) {
      const unsigned short* rp = qkv + row0 + (size_t)sl * QKV_N + h * HD;
      float q = bf2f(rp[d]), k = bf2f(rp[HIDDEN + d]);
      if (d < 16) {
        float c = cs0[sl][d], s = sn0[sl][d];
        float q2 = bf2f(rp[d + 16]), k2 = bf2f(rp[HIDDEN + d + 16]);
        qv = q * c - q2 * s;
        kv = k * c - k2 * s;
      } else if (d < 32) {
        float c = cs0[sl][d - 16], s = sn0[sl][d - 16];
        float q1 = bf2f(rp[d - 16]), k1 = bf2f(rp[HIDDEN + d - 16]);
        qv = q * c + q1 * s;
        kv = k * c + k1 * s;
      } else {
        qv = q; kv = k;
      }
    }
    Qw[obase + (size_t)sl * DPAD + d] = f2bf(qv * 0.111803398874989485f); // * 80^-0.5
    Kw[obase + (size_t)sl * DPAD + d] = f2bf(kv);
  }
  for (int i = tid; i < 64 * HD; i += 256) {
    int sl = i / HD, d = i - sl * HD;
    vbuf[sl][d] = qkv[row0 + (size_t)sl * QKV_N + 2 * HIDDEN + h * HD + d];
  }
  __syncthreads();
  const size_t vtb = (size_t)bh * DPAD * S_LEN + s0;
  for (int i = tid; i < DPAD * 64; i += 256) {
    int d = i >> 6, sl = i & 63;
    Vt[vtb + (size_t)d * S_LEN + sl] = (d < HD) ? vbuf[sl][d] : (unsigned short)0;
  }
}

// ---------------- flash attention (causal), QBLK=128, KVBLK=64 ----------------
__global__ __launch_bounds__(256, 2) void k_attn(const unsigned short* __restrict__ Qw,
                                                 const unsigned short* __restrict__ Kw,
                                                 const unsigned short* __restrict__ Vt,
                                                 unsigned short* __restrict__ O) {
  __shared__ unsigned short sK[2][64 * 104];
  __shared__ unsigned short sV[2][80 * 72];
  __shared__ unsigned short sP[4][16 * 72];
  const int p = blockIdx.x;
  const int bh = blockIdx.y;
  const int b = bh >> 5, h = bh & 31;
  const int tid = threadIdx.x;
  const int wave = tid >> 6, lane = tid & 63;
  const int lr = lane >> 4, lc = lane & 15;
  unsigned short* Pw = &sP[wave][0];

  const unsigned short* Kh = Kw + (size_t)bh * S_LEN * DPAD;
  const unsigned short* Vh = Vt + (size_t)bh * DPAD * S_LEN;
  const unsigned short* Qh = Qw + (size_t)bh * S_LEN * DPAD;

  const int kr = tid >> 2, kc = (tid & 3) * 24;
  const int vr = tid >> 3, vc = (tid & 7) * 8;

  u16x8 kst0, kst1, kst2, vst0, vst1, vst2;
  auto gload = [&](int t) {
    const unsigned short* Kg = Kh + ((size_t)(t * 64 + kr)) * DPAD + kc;
    kst0 = *(const u16x8*)(Kg);
    kst1 = *(const u16x8*)(Kg + 8);
    kst2 = *(const u16x8*)(Kg + 16);
    const unsigned short* Vg = Vh + (size_t)vr * S_LEN + t * 64 + vc;
    vst0 = *(const u16x8*)(Vg);
    vst1 = *(const u16x8*)(Vg + 32 * S_LEN);
    if (tid < 128) vst2 = *(const u16x8*)(Vg + (size_t)64 * S_LEN);
  };
  auto swrite = [&](int buf) {
    *(u16x8*)&sK[buf][kr * 104 + kc] = kst0;
    *(u16x8*)&sK[buf][kr * 104 + kc + 8] = kst1;
    *(u16x8*)&sK[buf][kr * 104 + kc + 16] = kst2;
    *(u16x8*)&sV[buf][vr * 72 + vc] = vst0;
    *(u16x8*)&sV[buf][(vr + 32) * 72 + vc] = vst1;
    if (tid < 128) *(u16x8*)&sV[buf][(vr + 64) * 72 + vc] = vst2;
  };

  const f32x4 zero = {0.f, 0.f, 0.f, 0.f};

#pragma unroll 1
  for (int qi = 0; qi < 2; ++qi) {
    const int qt = qi ? (15 - p) : p;
    const int nt = 2 * qt + 2;
    const int wbase = qt * 128 + wave * 32;

    bf16x8 qf[2][3];
#pragma unroll
    for (int m = 0; m < 2; ++m)
#pragma unroll
      for (int ks = 0; ks < 3; ++ks)
        qf[m][ks] = *(const bf16x8*)&Qh[(size_t)(wbase + m * 16 + lc) * DPAD + ks * 32 + lr * 8];

    f32x4 oacc[2][5];
#pragma unroll
    for (int m = 0; m < 2; ++m)
#pragma unroll
      for (int n = 0; n < 5; ++n) oacc[m][n] = zero;
    float mrun[2] = {-1e30f, -1e30f}, lrun[2] = {0.f, 0.f};

    gload(0);
    __syncthreads();
    swrite(0);
    int cur = 0;

#pragma unroll 1
    for (int t = 0; t < nt; ++t) {
      __syncthreads();
      if (t + 1 < nt) gload(t + 1);
      const int ktb = t * 64;
      const bool act0 = ktb <= wbase + 15;
      const bool act1 = ktb <= wbase + 31;
      if (act1) {
        const unsigned short* Kc = sK[cur];
        const unsigned short* Vc = sV[cur];
        f32x4 sf[2][4];
#pragma unroll
        for (int n = 0; n < 4; ++n) {
          sf[0][n] = zero; sf[1][n] = zero;
#pragma unroll
          for (int ks = 0; ks < 3; ++ks) {
            bf16x8 kf = *(const bf16x8*)&Kc[(n * 16 + lc) * 104 + ks * 32 + lr * 8];
            if (act0) sf[0][n] = __builtin_amdgcn_mfma_f32_16x16x32_bf16(kf, qf[0][ks], sf[0][n], 0, 0, 0);
            sf[1][n] = __builtin_amdgcn_mfma_f32_16x16x32_bf16(kf, qf[1][ks], sf[1][n], 0, 0, 0);
          }
        }
        bf16x8 vf[5][2];
#pragma unroll
        for (int n = 0; n < 5; ++n)
#pragma unroll
          for (int ks = 0; ks < 2; ++ks)
            vf[n][ks] = *(const bf16x8*)&Vc[(n * 16 + lc) * 72 + ks * 32 + lr * 8];
#pragma unroll
        for (int m = 0; m < 2; ++m) {
          if (m == 0 && !act0) continue;
          const int qrow0 = wbase + m * 16;
          if (ktb + 63 > qrow0) {
#pragma unroll
            for (int n = 0; n < 4; ++n)
#pragma unroll
              for (int j = 0; j < 4; ++j)
                if (ktb + n * 16 + lr * 4 + j > qrow0 + lc) sf[m][n][j] = -1e30f;
          }
          float t0 = sf[m][0][0];
#pragma unroll
          for (int n = 0; n < 4; ++n)
#pragma unroll
            for (int j = 0; j < 4; ++j) t0 = fmaxf(t0, sf[m][n][j]);
          t0 = fmaxf(t0, __shfl_xor(t0, 16));
          t0 = fmaxf(t0, __shfl_xor(t0, 32));
          const float nm = fmaxf(mrun[m], t0);
          const float corrq = __expf(mrun[m] - nm);
          mrun[m] = nm;
          float ps = 0.f;
#pragma unroll
          for (int n = 0; n < 4; ++n)
#pragma unroll
            for (int j = 0; j < 4; ++j) {
              float e = __expf(sf[m][n][j] - nm);
              sf[m][n][j] = e;
              ps += e;
            }
          ps += __shfl_xor(ps, 16);
          ps += __shfl_xor(ps, 32);
          lrun[m] = lrun[m] * corrq + ps;
          float cj[4];
#pragma unroll
          for (int j = 0; j < 4; ++j) cj[j] = __shfl(corrq, lr * 4 + j, 16);
#pragma unroll
          for (int n = 0; n < 5; ++n)
#pragma unroll
            for (int j = 0; j < 4; ++j) oacc[m][n][j] *= cj[j];
#pragma unroll
          for (int n = 0; n < 4; ++n) {
            unsigned lo = (unsigned)f2bf(sf[m][n][0]) | ((unsigned)f2bf(sf[m][n][1]) << 16);
            unsigned hi = (unsigned)f2bf(sf[m][n][2]) | ((unsigned)f2bf(sf[m][n][3]) << 16);
            uint2 u; u.x = lo; u.y = hi;
            *(uint2*)&Pw[lc * 72 + n * 16 + lr * 4] = u;
          }
          asm volatile("" ::: "memory");
          bf16x8 pa0 = *(const bf16x8*)&Pw[lc * 72 + lr * 8];
          bf16x8 pa1 = *(const bf16x8*)&Pw[lc * 72 + 32 + lr * 8];
#pragma unroll
          for (int n = 0; n < 5; ++n) {
            oacc[m][n] = __builtin_amdgcn_mfma_f32_16x16x32_bf16(pa0, vf[n][0], oacc[m][n], 0, 0, 0);
            oacc[m][n] = __builtin_amdgcn_mfma_f32_16x16x32_bf16(pa1, vf[n][1], oacc[m][n], 0, 0, 0);
          }
          asm volatile("" ::: "memory");
        }
      }
      if (t + 1 < nt) swrite(cur ^ 1);
      cur ^= 1;
    }

#pragma unroll
    for (int m = 0; m < 2; ++m) {
      float linv[4];
#pragma unroll
      for (int j = 0; j < 4; ++j) {
        float lj = __shfl(lrun[m], lr * 4 + j, 16);
        linv[j] = 1.f / lj;
      }
      const int q0 = wbase + m * 16 + lr * 4;
#pragma unroll
      for (int n = 0; n < 5; ++n) {
        const int d = n * 16 + lc;
#pragma unroll
        for (int j = 0; j < 4; ++j)
          O[((size_t)(b * S_LEN) + q0 + j) * HIDDEN + h * HD + d] = f2bf(oacc[m][n][j] * linv[j]);
      }
    }
  }
}

extern "C" void kernel_launch(void* const* d_in, const int* in_sizes, int n_in,
                              void* d_out, int out_size, void* d_ws, size_t ws_size,
                              hipStream_t stream) {
  (void)in_sizes; (void)n_in; (void)out_size; (void)ws_size;
  const float* hidden  = (const float*)d_in[1];
  const float* w_qkv   = (const float*)d_in[2];
  const float* b_qkv   = (const float*)d_in[3];
  const float* w_dense = (const float*)d_in[4];
  const float* b_dense = (const float*)d_in[5];
  char* ws = (char*)d_ws;
  unsigned short* Abf   = (unsigned short*)(ws + 0);          // 4096x2560 bf16
  unsigned short* Wqkvt = (unsigned short*)(ws + 20971520);   // 7680x2560 bf16
  unsigned short* Wdt   = (unsigned short*)(ws + 60293120);   // 2560x2560 bf16
  unsigned short* QKVb  = (unsigned short*)(ws + 73400320);   // 4096x7680 bf16
  unsigned short* Qw    = (unsigned short*)(ws + 136314880);  // 64x2048x96 bf16
  unsigned short* Kw    = (unsigned short*)(ws + 161480704);
  unsigned short* Vt    = (unsigned short*)(ws + 186646528);
  unsigned short* Obf   = (unsigned short*)(ws + 211812352);  // 4096x2560 bf16

  k_cvt<<<10240, 256, 0, stream>>>(hidden, Abf, 2621440);
  k_transpose_bf16<<<dim3(120, 40), 256, 0, stream>>>(w_qkv, Wqkvt, 2560, 7680);
  k_transpose_bf16<<<dim3(40, 40), 256, 0, stream>>>(w_dense, Wdt, 2560, 2560);
  k_gemm_qkv<<<480, 512, 0, stream>>>(Abf, Wqkvt, b_qkv, QKVb, 4096, 7680, 2560);
  k_rope<<<2048, 256, 0, stream>>>(QKVb, Qw, Kw, Vt);
  k_attn<<<dim3(8, 64), 256, 0, stream>>>(Qw, Kw, Vt, Obf);
  k_gemm_out<<<640, 256, 0, stream>>>(Obf, Wdt, b_dense, (float*)d_out, 4096, 2560, 2560);
}